// Round 14
// baseline (315.739 us; speedup 1.0000x reference)
//
#include <hip/hip_runtime.h>
#include <math.h>

#define N_NODES 10000
#define N_EDGES 320000
#define DIM 256
#define ND ((size_t)N_NODES * DIM)

typedef float f32x4 __attribute__((ext_vector_type(4)));
typedef short s16x8 __attribute__((ext_vector_type(8)));
typedef short s16x4 __attribute__((ext_vector_type(4)));

__device__ __forceinline__ float relu6f(float x) { return fminf(fmaxf(x, 0.f), 6.f); }

__device__ __forceinline__ short f2bf(float x) {
  unsigned u = __builtin_bit_cast(unsigned, x);
  unsigned r = (u + 0x7fffu + ((u >> 16) & 1u)) >> 16;
  return (short)r;
}
__device__ __forceinline__ float bf2f(short b) {
  unsigned u = ((unsigned)(unsigned short)b) << 16;
  return __builtin_bit_cast(float, u);
}
__device__ __forceinline__ float bflo(unsigned u) {
  return __builtin_bit_cast(float, u << 16);
}
__device__ __forceinline__ float bfhi(unsigned u) {
  return __builtin_bit_cast(float, u & 0xffff0000u);
}

// ---------------- combined prologue ----------------
// blocks 0..63   : transpose+split WQ/WK/WV/Wo (4 matrices x 16 tiles)
// blocks 64..67  : transpose+split W1 [256x64]
// blocks 68..71  : transpose+split W2 [64x256]
// blocks 72..1321: degree histograms (1250 blocks x 256 threads)
__global__ __launch_bounds__(256) void k_prologue(
    const float* __restrict__ WQ, const float* __restrict__ WK,
    const float* __restrict__ WV, const float* __restrict__ Wo,
    const float* __restrict__ W1, const float* __restrict__ W2,
    short* __restrict__ Wt_hi, short* __restrict__ Wt_lo,
    short* __restrict__ W1h, short* __restrict__ W1l,
    short* __restrict__ W2h, short* __restrict__ W2l,
    const int* __restrict__ src, const int* __restrict__ dst,
    int* __restrict__ outc, int* __restrict__ inc) {
  __shared__ float tile[64][65];
  int bid = blockIdx.x, t = threadIdx.x;
  if (bid < 72) {
    const float* W;
    short *hi, *lo;
    int K, N, tk, tn;
    if (bid < 64) {
      int mat = bid >> 4, tl = bid & 15;
      W = (mat == 0) ? WQ : (mat == 1) ? WK : (mat == 2) ? WV : Wo;
      hi = Wt_hi + (size_t)mat * 65536;
      lo = Wt_lo + (size_t)mat * 65536;
      K = 256; N = 256;
      tk = (tl >> 2) * 64; tn = (tl & 3) * 64;
    } else if (bid < 68) {
      W = W1; hi = W1h; lo = W1l;
      K = 256; N = 64;
      tk = (bid - 64) * 64; tn = 0;
    } else {
      W = W2; hi = W2h; lo = W2l;
      K = 64; N = 256;
      tk = 0; tn = (bid - 68) * 64;
    }
    int r = t >> 4, c4 = (t & 15) * 4;
#pragma unroll
    for (int p = 0; p < 4; p++) {
      float4 v4 = *(const float4*)(W + (size_t)(tk + p * 16 + r) * N + tn + c4);
      tile[p * 16 + r][c4 + 0] = v4.x;
      tile[p * 16 + r][c4 + 1] = v4.y;
      tile[p * 16 + r][c4 + 2] = v4.z;
      tile[p * 16 + r][c4 + 3] = v4.w;
    }
    __syncthreads();
    int nl = t >> 2, q = t & 3;
    s16x8 h0, h1, l0, l1;
#pragma unroll
    for (int j = 0; j < 8; j++) {
      float x = tile[q * 16 + j][nl];
      short hb = f2bf(x);
      h0[j] = hb; l0[j] = f2bf(x - bf2f(hb));
    }
#pragma unroll
    for (int j = 0; j < 8; j++) {
      float x = tile[q * 16 + 8 + j][nl];
      short hb = f2bf(x);
      h1[j] = hb; l1[j] = f2bf(x - bf2f(hb));
    }
    size_t base = (size_t)(tn + nl) * K + tk + q * 16;
    *(s16x8*)(hi + base) = h0;
    *(s16x8*)(hi + base + 8) = h1;
    *(s16x8*)(lo + base) = l0;
    *(s16x8*)(lo + base + 8) = l1;
  } else {
    int e = (bid - 72) * 256 + t;
    if (e < N_EDGES) {
      atomicAdd(&outc[src[e]], 1);
      atomicAdd(&inc[dst[e]], 1);
    }
  }
}

// ---------------- exclusive scan + softmax logZ (single block) ----------------
__global__ void k_scan(const int* __restrict__ inc, const int* __restrict__ outc,
                       int* __restrict__ rowptr, int* __restrict__ nextp,
                       float* __restrict__ logzf) {
  __shared__ int wsum[16];
  __shared__ double dsum[16];
  __shared__ int carry_s;
  int tid = threadIdx.x, lane = tid & 63, wid = tid >> 6;

  double e = 0.0;
  for (int i = tid; i < N_NODES; i += 1024) e += exp((double)(inc[i] + outc[i]));
#pragma unroll
  for (int off = 1; off < 64; off <<= 1) e += __shfl_xor(e, off);
  if (lane == 0) dsum[wid] = e;
  __syncthreads();
  if (tid == 0) {
    double Z = 0.0;
#pragma unroll
    for (int i = 0; i < 16; i++) Z += dsum[i];
    logzf[0] = (float)log(Z);
    carry_s = 0;
  }
  __syncthreads();

  for (int base = 0; base < N_NODES; base += 1024) {
    int i = base + tid;
    int v = (i < N_NODES) ? inc[i] : 0;
    int x = v;
#pragma unroll
    for (int off = 1; off < 64; off <<= 1) {
      int t = __shfl_up(x, off);
      if (lane >= off) x += t;
    }
    if (lane == 63) wsum[wid] = x;
    __syncthreads();
    if (wid == 0 && lane < 16) {
      int wv = wsum[lane];
#pragma unroll
      for (int off = 1; off < 16; off <<= 1) {
        int t = __shfl_up(wv, off);
        if (lane >= off) wv += t;
      }
      wsum[lane] = wv;
    }
    __syncthreads();
    int carry = carry_s;
    int wadd = (wid > 0) ? wsum[wid - 1] : 0;
    int excl = carry + wadd + x - v;
    if (i < N_NODES) {
      rowptr[i] = excl;
      nextp[i] = excl;
    }
    __syncthreads();
    if (tid == 1023) carry_s = excl + v;
    __syncthreads();
  }
  if (tid == 0) rowptr[N_NODES] = carry_s;
}

// ---------------- combined CSR fill + A presplit ----------------
__global__ __launch_bounds__(256) void k_fillsplit(
    const int* __restrict__ src, const int* __restrict__ dst,
    int* __restrict__ nextp, int* __restrict__ csr_src,
    const float* __restrict__ v, const int* __restrict__ inc,
    const int* __restrict__ outc, const float* __restrict__ logzf,
    short* __restrict__ Ahg, short* __restrict__ Alg) {
  int bid = blockIdx.x, t = threadIdx.x;
  int e = bid * 256 + t;
  if (e < N_EDGES) {
    int pos = atomicAdd(&nextp[dst[e]], 1);
    csr_src[pos] = src[e];
  }
  size_t idx = ((size_t)bid * 256 + t) * 4;
  int row = (int)(idx >> 8);
  float c = __expf((float)(inc[row] + outc[row]) - logzf[0]);
  float4 x = *(const float4*)(v + idx);
  float xs[4] = {x.x * c, x.y * c, x.z * c, x.w * c};
  s16x4 h, l;
#pragma unroll
  for (int j = 0; j < 4; j++) {
    short hb = f2bf(xs[j]);
    h[j] = hb;
    l[j] = f2bf(xs[j] - bf2f(hb));
  }
  *(s16x4*)(Ahg + idx) = h;
  *(s16x4*)(Alg + idx) = l;
}

// ---------------- bf16-split MFMA GEMM (A pre-split in global) ----------------
template <int KVMODE>
__global__ __launch_bounds__(256) void k_gemm_mfma(
    const short* __restrict__ Ahg, const short* __restrict__ Alg,
    const short* __restrict__ Whi, const short* __restrict__ Wlo,
    const float* __restrict__ b0, const float* __restrict__ b1,
    const float* __restrict__ b2, float* __restrict__ Qout,
    unsigned short* __restrict__ KVout, float* __restrict__ Cbase,
    float* __restrict__ bnsum, float* __restrict__ bnsq, int M) {
  const float* bias = (blockIdx.z == 0) ? b0 : (blockIdx.z == 1) ? b1 : b2;
  const short* whi = Whi + (size_t)blockIdx.z * 65536;
  const short* wlo = Wlo + (size_t)blockIdx.z * 65536;

  __shared__ __align__(16) short Ah[64][40];
  __shared__ __align__(16) short Al[64][40];
  __shared__ __align__(16) short Bh[128][40];
  __shared__ __align__(16) short Bl[128][40];

  int tid = threadIdx.x;
  int lane = tid & 63, wid = tid >> 6;
  int wm = wid >> 1, wn = wid & 1;
  int m0 = blockIdx.x * 64;
  int n0g = blockIdx.y * 128;

  f32x4 acc[2][4];
#pragma unroll
  for (int i = 0; i < 2; i++)
#pragma unroll
    for (int j = 0; j < 4; j++) acc[i][j] = (f32x4){0.f, 0.f, 0.f, 0.f};

  int sa_row = tid >> 2, sa_seg = tid & 3;
  int sb_row = tid >> 1, sb_seg = tid & 1;
  const s16x8 zero8 = {0, 0, 0, 0, 0, 0, 0, 0};

  for (int k0 = 0; k0 < 256; k0 += 32) {
    __syncthreads();
    {
      int m = m0 + sa_row;
      s16x8 h = zero8, l = zero8;
      if (m < M) {
        size_t ga = (size_t)m * 256 + k0 + sa_seg * 8;
        h = *(const s16x8*)(Ahg + ga);
        l = *(const s16x8*)(Alg + ga);
      }
      *(s16x8*)&Ah[sa_row][sa_seg * 8] = h;
      *(s16x8*)&Al[sa_row][sa_seg * 8] = l;
    }
    {
      size_t gb = (size_t)(n0g + sb_row) * 256 + k0 + sb_seg * 16;
      *(s16x8*)&Bh[sb_row][sb_seg * 16] = *(const s16x8*)(whi + gb);
      *(s16x8*)&Bh[sb_row][sb_seg * 16 + 8] = *(const s16x8*)(whi + gb + 8);
      *(s16x8*)&Bl[sb_row][sb_seg * 16] = *(const s16x8*)(wlo + gb);
      *(s16x8*)&Bl[sb_row][sb_seg * 16 + 8] = *(const s16x8*)(wlo + gb + 8);
    }
    __syncthreads();
    int arow0 = wm * 32 + (lane & 15);
    int kc = (lane >> 4) * 8;
    s16x8 ah[2], al[2], bh[4], bl[4];
#pragma unroll
    for (int mf = 0; mf < 2; mf++) {
      ah[mf] = *(const s16x8*)&Ah[arow0 + mf * 16][kc];
      al[mf] = *(const s16x8*)&Al[arow0 + mf * 16][kc];
    }
    int brow0 = wn * 64 + (lane & 15);
#pragma unroll
    for (int nf = 0; nf < 4; nf++) {
      bh[nf] = *(const s16x8*)&Bh[brow0 + nf * 16][kc];
      bl[nf] = *(const s16x8*)&Bl[brow0 + nf * 16][kc];
    }
#pragma unroll
    for (int mf = 0; mf < 2; mf++)
#pragma unroll
      for (int nf = 0; nf < 4; nf++) {
        acc[mf][nf] = __builtin_amdgcn_mfma_f32_16x16x32_bf16(ah[mf], bh[nf], acc[mf][nf], 0, 0, 0);
        acc[mf][nf] = __builtin_amdgcn_mfma_f32_16x16x32_bf16(al[mf], bh[nf], acc[mf][nf], 0, 0, 0);
        acc[mf][nf] = __builtin_amdgcn_mfma_f32_16x16x32_bf16(ah[mf], bl[nf], acc[mf][nf], 0, 0, 0);
      }
  }

  int colq = lane & 15, rowq = (lane >> 4) * 4;
  if (KVMODE == 1) {
    bool isq = (blockIdx.z == 0);
    int kvoff = (blockIdx.z == 1) ? 0 : 256;
#pragma unroll
    for (int mf = 0; mf < 2; mf++) {
#pragma unroll
      for (int nf = 0; nf < 4; nf++) {
        int n = wn * 64 + nf * 16 + colq;
        float bv = bias[n0g + n];
#pragma unroll
        for (int j = 0; j < 4; j++) {
          int m = m0 + wm * 32 + mf * 16 + rowq + j;
          if (m >= M) continue;
          float val = acc[mf][nf][j] + bv;
          if (isq) Qout[(size_t)m * 256 + n0g + n] = val;
          else KVout[(size_t)m * 512 + kvoff + n0g + n] = (unsigned short)f2bf(val);
        }
      }
    }
  } else {
    float cs[4], cq[4];
#pragma unroll
    for (int nf = 0; nf < 4; nf++) { cs[nf] = 0.f; cq[nf] = 0.f; }
#pragma unroll
    for (int nf = 0; nf < 4; nf++) {
      int n = wn * 64 + nf * 16 + colq;
      float bv = bias[n0g + n];
#pragma unroll
      for (int mf = 0; mf < 2; mf++) {
#pragma unroll
        for (int j = 0; j < 4; j++) {
          int m = m0 + wm * 32 + mf * 16 + rowq + j;
          if (m >= M) continue;
          float val = acc[mf][nf][j] + bv;
          Cbase[(size_t)m * 256 + n0g + n] = val;
          cs[nf] += val;
          cq[nf] = fmaf(val, val, cq[nf]);
        }
      }
    }
#pragma unroll
    for (int nf = 0; nf < 4; nf++) {
      float s = cs[nf], qq = cq[nf];
      s += __shfl_xor(s, 16); s += __shfl_xor(s, 32);
      qq += __shfl_xor(qq, 16); qq += __shfl_xor(qq, 32);
      if (lane < 16) {
        int n = n0g + wn * 64 + nf * 16 + lane;
        atomicAdd(&bnsum[n], s);
        atomicAdd(&bnsq[n], qq);
      }
    }
  }
}

// ---------------- per-head edge-score + aggregation ----------------
// One launch per head (serial on stream -> per-XCD L2 sees only this head's
// 2.56 MB k/v slice). Wave per node; 4 edges in flight via 4x16-lane groups
// (eg = lane>>4 picks edge, dl = lane&15 picks dim-quad). Score reduce = 4
// shfls for 4 edges (1/edge amortized); group partials folded at the end.
__global__ __launch_bounds__(256) void k_edgeagg_h(
    const int* __restrict__ rowptr, const int* __restrict__ csr_src,
    const float* __restrict__ q, const unsigned short* __restrict__ kv,
    short* __restrict__ att_h, short* __restrict__ att_l, int head) {
  int lane = threadIdx.x & 63, wid = threadIdx.x >> 6;
  int n = blockIdx.x * 4 + wid;
  int beg = rowptr[n], end = rowptr[n + 1];
  int eg = lane >> 4, dl = lane & 15;
  int hoff = head * 64 + dl * 4;
  float4 qv = *(const float4*)(q + (size_t)n * 256 + hoff);
  float a0 = 0.f, a1 = 0.f, a2 = 0.f, a3 = 0.f, z = 0.f;

  for (int i = beg; i < end; i += 4) {
    int idx = i + eg;
    bool ok = idx < end;
    int s = ok ? csr_src[idx] : 0;
    const unsigned short* rp = kv + (size_t)s * 512 + hoff;
    uint2 ku = *(const uint2*)rp;
    uint2 vu = *(const uint2*)(rp + 256);
    float p = bflo(ku.x) * qv.x + bfhi(ku.x) * qv.y +
              bflo(ku.y) * qv.z + bfhi(ku.y) * qv.w;
    p += __shfl_xor(p, 1);
    p += __shfl_xor(p, 2);
    p += __shfl_xor(p, 4);
    p += __shfl_xor(p, 8);
    float e0 = ok ? __expf(fminf(fmaxf(p * 0.125f, -5.f), 5.f)) : 0.f;
    a0 = fmaf(e0, bflo(vu.x), a0);
    a1 = fmaf(e0, bfhi(vu.x), a1);
    a2 = fmaf(e0, bflo(vu.y), a2);
    a3 = fmaf(e0, bfhi(vu.y), a3);
    z += e0;
  }

  // fold the 4 edge-groups (same dims, different edges)
  a0 += __shfl_xor(a0, 16); a0 += __shfl_xor(a0, 32);
  a1 += __shfl_xor(a1, 16); a1 += __shfl_xor(a1, 32);
  a2 += __shfl_xor(a2, 16); a2 += __shfl_xor(a2, 32);
  a3 += __shfl_xor(a3, 16); a3 += __shfl_xor(a3, 32);
  z  += __shfl_xor(z, 16);  z  += __shfl_xor(z, 32);

  if (eg == 0) {
    float invz = 1.f / z;
    float rs[4] = {a0 * invz, a1 * invz, a2 * invz, a3 * invz};
    s16x4 h, l;
#pragma unroll
    for (int j = 0; j < 4; j++) {
      short hb = f2bf(rs[j]);
      h[j] = hb;
      l[j] = f2bf(rs[j] - bf2f(hb));
    }
    size_t base_o = (size_t)n * 256 + hoff;
    *(s16x4*)(att_h + base_o) = h;
    *(s16x4*)(att_l + base_o) = l;
  }
}

// ---------------- fused BN-finalize + BN-apply + SE block (MFMA) ----------------
__global__ __launch_bounds__(256) void k_se2(
    const float* __restrict__ o,
    const float* __restrict__ bnsum, const float* __restrict__ bnsq,
    const float* __restrict__ gamma, const float* __restrict__ beta,
    const short* __restrict__ W1h, const short* __restrict__ W1l,
    const float* __restrict__ b1,
    const short* __restrict__ W2h, const short* __restrict__ W2l,
    const float* __restrict__ b2,
    const float* __restrict__ vin, float* __restrict__ out) {
  __shared__ __align__(16) short xh[64][264];
  __shared__ __align__(16) short xl[64][264];
  __shared__ __align__(16) short hh[64][72];
  __shared__ __align__(16) short hl[64][72];
  __shared__ float vt[64][256];
  __shared__ float scale_s[256], shift_s[256];

  int t = threadIdx.x;
  int lane = t & 63, w = t >> 6;
  int m0 = blockIdx.x * 64;

  {
    float mean = bnsum[t] * (1.f / N_NODES);
    float var = bnsq[t] * (1.f / N_NODES) - mean * mean;
    float istd = rsqrtf(var + 1e-5f);
    float sc = gamma[t] * istd;
    scale_s[t] = sc;
    shift_s[t] = beta[t] - mean * sc;
  }
  __syncthreads();

  {
    int r = t >> 2;
    int cb = (t & 3) * 4;
    int gr = m0 + r;
    bool rok = gr < N_NODES;
#pragma unroll
    for (int p = 0; p < 16; p++) {
      int c = cb + p * 16;
      float4 ov = make_float4(0.f, 0.f, 0.f, 0.f), vv = ov;
      if (rok) {
        ov = *(const float4*)(o + (size_t)gr * 256 + c);
        vv = *(const float4*)(vin + (size_t)gr * 256 + c);
      }
      float xs[4];
      xs[0] = relu6f(fmaf(ov.x, scale_s[c + 0], shift_s[c + 0]));
      xs[1] = relu6f(fmaf(ov.y, scale_s[c + 1], shift_s[c + 1]));
      xs[2] = relu6f(fmaf(ov.z, scale_s[c + 2], shift_s[c + 2]));
      xs[3] = relu6f(fmaf(ov.w, scale_s[c + 3], shift_s[c + 3]));
#pragma unroll
      for (int j = 0; j < 4; j++) {
        short hb = f2bf(xs[j]);
        xh[r][c + j] = hb;
        xl[r][c + j] = f2bf(xs[j] - bf2f(hb));
      }
      *(float4*)&vt[r][c] = vv;
    }
  }
  __syncthreads();

  int fr = lane & 15, fq = lane >> 4;
  int kc = fq * 8;
  int arow = w * 16 + fr;

  f32x4 acc1[4];
#pragma unroll
  for (int nf = 0; nf < 4; nf++) acc1[nf] = (f32x4){0.f, 0.f, 0.f, 0.f};
#pragma unroll
  for (int ks = 0; ks < 8; ks++) {
    s16x8 ah = *(const s16x8*)&xh[arow][ks * 32 + kc];
    s16x8 al = *(const s16x8*)&xl[arow][ks * 32 + kc];
#pragma unroll
    for (int nf = 0; nf < 4; nf++) {
      size_t bo_ = (size_t)(nf * 16 + fr) * 256 + ks * 32 + kc;
      s16x8 bh = *(const s16x8*)(W1h + bo_);
      s16x8 bl = *(const s16x8*)(W1l + bo_);
      acc1[nf] = __builtin_amdgcn_mfma_f32_16x16x32_bf16(ah, bh, acc1[nf], 0, 0, 0);
      acc1[nf] = __builtin_amdgcn_mfma_f32_16x16x32_bf16(al, bh, acc1[nf], 0, 0, 0);
      acc1[nf] = __builtin_amdgcn_mfma_f32_16x16x32_bf16(ah, bl, acc1[nf], 0, 0, 0);
    }
  }
#pragma unroll
  for (int nf = 0; nf < 4; nf++) {
    int n = nf * 16 + fr;
    float bv = b1[n];
#pragma unroll
    for (int j = 0; j < 4; j++) {
      int row = w * 16 + fq * 4 + j;
      float hv = relu6f(acc1[nf][j] + bv);
      short hb = f2bf(hv);
      hh[row][n] = hb;
      hl[row][n] = f2bf(hv - bf2f(hb));
    }
  }
  __syncthreads();

  f32x4 acc2[16];
#pragma unroll
  for (int nf = 0; nf < 16; nf++) acc2[nf] = (f32x4){0.f, 0.f, 0.f, 0.f};
#pragma unroll
  for (int ks = 0; ks < 2; ks++) {
    s16x8 ah = *(const s16x8*)&hh[arow][ks * 32 + kc];
    s16x8 al = *(const s16x8*)&hl[arow][ks * 32 + kc];
#pragma unroll
    for (int nf = 0; nf < 16; nf++) {
      size_t bo_ = (size_t)(nf * 16 + fr) * 64 + ks * 32 + kc;
      s16x8 bh = *(const s16x8*)(W2h + bo_);
      s16x8 bl = *(const s16x8*)(W2l + bo_);
      acc2[nf] = __builtin_amdgcn_mfma_f32_16x16x32_bf16(ah, bh, acc2[nf], 0, 0, 0);
      acc2[nf] = __builtin_amdgcn_mfma_f32_16x16x32_bf16(al, bh, acc2[nf], 0, 0, 0);
      acc2[nf] = __builtin_amdgcn_mfma_f32_16x16x32_bf16(ah, bl, acc2[nf], 0, 0, 0);
    }
  }
#pragma unroll
  for (int nf = 0; nf < 16; nf++) {
    int col = nf * 16 + fr;
    float bv = b2[col];
#pragma unroll
    for (int j = 0; j < 4; j++) {
      int row = w * 16 + fq * 4 + j;
      int grow = m0 + row;
      if (grow < N_NODES) {
        float se = acc2[nf][j] + bv;
        float hs = se * relu6f(se + 3.f) * (1.f / 6.f);
        float xr = bf2f(xh[row][col]) + bf2f(xl[row][col]);
        out[(size_t)grow * 256 + col] = fmaf(hs, xr, vt[row][col]);
      }
    }
  }
}

extern "C" void kernel_launch(void* const* d_in, const int* in_sizes, int n_in,
                              void* d_out, int out_size, void* d_ws, size_t ws_size,
                              hipStream_t stream) {
  const float* v     = (const float*)d_in[0];
  const float* WQ    = (const float*)d_in[1];
  const float* bQ    = (const float*)d_in[2];
  const float* WK    = (const float*)d_in[3];
  const float* bK    = (const float*)d_in[4];
  const float* WV    = (const float*)d_in[5];
  const float* bV    = (const float*)d_in[6];
  const float* Wo    = (const float*)d_in[7];
  const float* bo    = (const float*)d_in[8];
  const float* W1    = (const float*)d_in[9];
  const float* b1    = (const float*)d_in[10];
  const float* W2    = (const float*)d_in[11];
  const float* b2    = (const float*)d_in[12];
  const float* gamma = (const float*)d_in[13];
  const float* beta  = (const float*)d_in[14];
  const int* srcI    = (const int*)d_in[15];
  const int* dstI    = (const int*)d_in[16];
  float* out = (float*)d_out;

  char* w = (char*)d_ws;
  size_t off = 0;
  auto take = [&](size_t bytes) {
    size_t o = off;
    off += (bytes + 255) & ~(size_t)255;
    return o;
  };
  // zeroed region (single memset): inc | outc | bnsum | bnsq
  int* inc      = (int*)(w + take(N_NODES * 4));
  int* outc     = (int*)(w + take(N_NODES * 4));
  float* bnsum  = (float*)(w + take(256 * 4));
  float* bnsq   = (float*)(w + take(256 * 4));
  size_t zero_span = off;
  float* logzf  = (float*)(w + take(4));
  float* q      = (float*)(w + take(ND * 4));
  unsigned short* kvb = (unsigned short*)(w + take((size_t)N_NODES * 512 * 2));
  short* Ahg    = (short*)(w + take(ND * 2));
  short* Alg    = (short*)(w + take(ND * 2));
  short* att_h  = (short*)(w + take(ND * 2));
  short* att_l  = (short*)(w + take(ND * 2));
  int* rowptr   = (int*)(w + take((N_NODES + 1) * 4));
  int* nextp    = (int*)(w + take(N_NODES * 4));
  int* csr_src  = (int*)(w + take((size_t)N_EDGES * 4));
  short* Wt_hi  = (short*)(w + take((size_t)4 * 65536 * 2));
  short* Wt_lo  = (short*)(w + take((size_t)4 * 65536 * 2));
  short* W1h    = (short*)(w + take((size_t)16384 * 2));
  short* W1l    = (short*)(w + take((size_t)16384 * 2));
  short* W2h    = (short*)(w + take((size_t)16384 * 2));
  short* W2l    = (short*)(w + take((size_t)16384 * 2));

  float* o = (float*)kvb;      // reuse: kv dead after edgeagg

  hipMemsetAsync(w, 0, zero_span, stream);

  k_prologue<<<dim3(1322), dim3(256), 0, stream>>>(
      WQ, WK, WV, Wo, W1, W2, Wt_hi, Wt_lo, W1h, W1l, W2h, W2l,
      srcI, dstI, outc, inc);

  k_scan<<<dim3(1), dim3(1024), 0, stream>>>(inc, outc, rowptr, nextp, logzf);

  k_fillsplit<<<dim3(2500), dim3(256), 0, stream>>>(
      srcI, dstI, nextp, csr_src, v, inc, outc, logzf, Ahg, Alg);

  // q (fp32), k/vv (bf16 interleaved) = A @ {WQ,WK,WV} + b
  k_gemm_mfma<1><<<dim3(157, 2, 3), dim3(256), 0, stream>>>(
      Ahg, Alg, Wt_hi, Wt_lo, bQ, bK, bV, q, kvb, nullptr, nullptr, nullptr, N_NODES);

  // per-head passes: serial on the stream so each pass's 2.56 MB k/v slice
  // is L2-resident per XCD
  for (int h = 0; h < 4; h++)
    k_edgeagg_h<<<dim3(N_NODES / 4), dim3(256), 0, stream>>>(
        rowptr, csr_src, q, kvb, att_h, att_l, h);

  // o = att @ Wo + bo, with fused BN column stats
  k_gemm_mfma<0><<<dim3(157, 2, 1), dim3(256), 0, stream>>>(
      att_h, att_l, Wt_hi + (size_t)3 * 65536, Wt_lo + (size_t)3 * 65536,
      bo, bo, bo, nullptr, nullptr, o, bnsum, bnsq, N_NODES);

  k_se2<<<dim3((N_NODES + 63) / 64), dim3(256), 0, stream>>>(
      o, bnsum, bnsq, gamma, beta, W1h, W1l, b1, W2h, W2l, b2, v, out);
}